// Round 1
// baseline (463.671 us; speedup 1.0000x reference)
//
#include <hip/hip_runtime.h>
#include <cstdint>
#include <cstddef>

typedef unsigned short ushort_t;
typedef __attribute__((ext_vector_type(8))) __bf16 bf16x8;
typedef __attribute__((ext_vector_type(4))) float f32x4;

#define DEVINL __device__ __forceinline__

DEVINL ushort_t f2bf(float f) {
  union { __bf16 b; ushort_t u; } v;
  v.b = (__bf16)f;  // v_cvt to bf16, RNE — bit-identical to manual round
  return v.u;
}
DEVINL float bf2f(ushort_t u) {
  union { unsigned u; float f; } v; v.u = ((unsigned)u) << 16;
  return v.f;
}

DEVINL float wred_sum(float x) {
#pragma unroll
  for (int o = 32; o > 0; o >>= 1) x += __shfl_xor(x, o, 64);
  return x;
}

// async global->LDS, 16B per lane (global_load_lds_dwordx4)
DEVINL void async16(ushort_t* lds, const ushort_t* g) {
  __builtin_amdgcn_global_load_lds(
      (__attribute__((address_space(1))) const unsigned int*)g,
      (__attribute__((address_space(3))) unsigned int*)lds, 16, 0, 0);
}

template <int CPR>
DEVINL int fswz(int r) {
  if constexpr (CPR == 4) return (r >> 2) & 3;
  else return r & 7;  // CPR==8
}

// chunk swizzle for the [rows][32]-ushort half-K slots (2-bit chunk id)
DEVINL int hswz(int r) { return (r & 3) ^ ((r >> 2) & 3); }

// ---------------- GroupNorm ----------------
__global__ __launch_bounds__(256) void gn_stats_k(const float* __restrict__ x,
                                                  float* __restrict__ stats) {
  const int bg = blockIdx.x;
  const float4* base = (const float4*)(x + ((size_t)bg << 16));
  float s = 0.f, q = 0.f;
  for (int i = threadIdx.x; i < 16384; i += 256) {
    float4 f = base[i];
    s += f.x + f.y + f.z + f.w;
    q += f.x * f.x + f.y * f.y + f.z * f.z + f.w * f.w;
  }
  s = wred_sum(s);
  q = wred_sum(q);
  __shared__ float rs[4], rq[4];
  const int lane = threadIdx.x & 63, wid = threadIdx.x >> 6;
  if (lane == 0) { rs[wid] = s; rq[wid] = q; }
  __syncthreads();
  if (threadIdx.x == 0) {
    float S = rs[0] + rs[1] + rs[2] + rs[3];
    float Q = rq[0] + rq[1] + rq[2] + rq[3];
    float mean = S * (1.f / 65536.f);
    float var = Q * (1.f / 65536.f) - mean * mean;
    stats[2 * bg] = mean;
    stats[2 * bg + 1] = rsqrtf(var + 1e-5f);
  }
}

__global__ __launch_bounds__(256) void gn_apply_k(const float* __restrict__ x,
                                                  const float* __restrict__ stats,
                                                  const float* __restrict__ gs,
                                                  const float* __restrict__ gb,
                                                  ushort_t* __restrict__ h) {
  __shared__ ushort_t tile[32][33];
  const int bid = blockIdx.x;
  const int b = bid >> 11;
  const int r = bid & 2047;
  const int ct = r >> 7, nt = r & 127;
  const int c0 = ct << 5, n0 = nt << 5;
  const int tx = threadIdx.x & 31, ty = threadIdx.x >> 5;
#pragma unroll
  for (int i = 0; i < 4; ++i) {
    const int c = c0 + ty + i * 8;
    const float mean = stats[2 * (b * 32 + (c >> 4))];
    const float rstd = stats[2 * (b * 32 + (c >> 4)) + 1];
    const float xv = x[(((size_t)b * 512 + c) << 12) + n0 + tx];
    tile[ty + i * 8][tx] = f2bf((xv - mean) * rstd * gs[c] + gb[c]);
  }
  __syncthreads();
#pragma unroll
  for (int i = 0; i < 4; ++i) {
    const int n = n0 + ty + i * 8;
    h[(((size_t)b << 12) + n) * 512 + c0 + tx] = tile[tx][ty + i * 8];
  }
}

// fp32 -> bf16 convert with per-matrix scale (sc folded into wq)
struct Ptr4 { const float* src[4]; float wsc[4]; };
__global__ __launch_bounds__(256) void cvt_all_k(Ptr4 s, ushort_t* __restrict__ dst) {
  const int i = blockIdx.x * 256 + threadIdx.x;
  const int m = i >> 18;
  dst[i] = f2bf(s.src[m][i & 262143] * s.wsc[m]);
}

// ---------------- NT GEMM (128x128, 2-barrier): C[M,N] = A[M,K] * B[N,K]^T ----
// EPI 2: fp32 transposed out + resid + bias (final projection).
// EPI 3: QKV fused, z picks weight/bias/out; z==2 (V) writes transposed [C][N].
struct Ptr3 { const float* bias[3]; ushort_t* out[3]; float bs[3]; };

template <int BM, int BN, int BK, int EPI>
__global__ __launch_bounds__(256) void gemm_nt_k(
    const ushort_t* __restrict__ A, int lda, const ushort_t* __restrict__ Bm, int ldb,
    void* __restrict__ Cout, int ldc, const float* __restrict__ bias,
    const float* __restrict__ resid, float scale, int K,
    size_t azs, size_t bzs, size_t czs, Ptr3 p3, float* __restrict__ lbuf) {
  constexpr int CPR = BK / 8;
  constexpr int WTM = BM / 2, WTN = BN / 2;
  constexpr int MI = WTM / 16, NI = WTN / 16;
  constexpr int AR = (BM * CPR) / 256;
  constexpr int BR = (BN * CPR) / 256;
  __shared__ ushort_t Als[BM * BK];
  __shared__ ushort_t Bls[BN * BK];
  const int tid = threadIdx.x;
  const int lane = tid & 63;
  const int wid = tid >> 6;
  const int quad = lane >> 4;
  const int r16 = lane & 15;
  const int wm = wid >> 1, wn = wid & 1;
  const int m0 = blockIdx.y * BM;
  const int n0 = blockIdx.x * BN;
  const int zb = blockIdx.z;

  A += azs * zb;
  Bm += bzs * zb;

  f32x4 acc[MI][NI] = {};

  for (int kt = 0; kt < K; kt += BK) {
#pragma unroll
    for (int r = 0; r < AR; ++r) {
      const int s = r * 256 + tid;
      const int row = s / CPR;
      const int q = (s % CPR) ^ fswz<CPR>(row);
      async16(&Als[s << 3], A + (size_t)(m0 + row) * lda + kt + (q << 3));
    }
#pragma unroll
    for (int r = 0; r < BR; ++r) {
      const int s = r * 256 + tid;
      const int row = s / CPR;
      const int q = (s % CPR) ^ fswz<CPR>(row);
      async16(&Bls[s << 3], Bm + (size_t)(n0 + row) * ldb + kt + (q << 3));
    }
    __syncthreads();
#pragma unroll
    for (int kf = 0; kf < BK / 32; ++kf) {
      bf16x8 af[MI], bfr[NI];
#pragma unroll
      for (int mi = 0; mi < MI; ++mi) {
        const int lr = wm * WTM + mi * 16 + r16;
        const int ch = kf * 4 + quad;
        af[mi] = *reinterpret_cast<const bf16x8*>(
            &Als[(lr * CPR + (ch ^ fswz<CPR>(lr))) << 3]);
      }
#pragma unroll
      for (int ni = 0; ni < NI; ++ni) {
        const int lr = wn * WTN + ni * 16 + r16;
        const int ch = kf * 4 + quad;
        bfr[ni] = *reinterpret_cast<const bf16x8*>(
            &Bls[(lr * CPR + (ch ^ fswz<CPR>(lr))) << 3]);
      }
#pragma unroll
      for (int mi = 0; mi < MI; ++mi)
#pragma unroll
        for (int ni = 0; ni < NI; ++ni)
          acc[mi][ni] = __builtin_amdgcn_mfma_f32_16x16x32_bf16(
              af[mi], bfr[ni], acc[mi][ni], 0, 0, 0);
    }
    __syncthreads();
  }

  const int mrow = m0 + wm * WTM;
  const int ncol = n0 + wn * WTN;
  if constexpr (EPI == 2) {  // final: fp32 transposed out + resid + bias
    float* C = (float*)Cout;
#pragma unroll
    for (int ni = 0; ni < NI; ++ni) {
      const int col = ncol + ni * 16 + r16;
      const float bvv = bias[col];
#pragma unroll
      for (int mi = 0; mi < MI; ++mi) {
        const int rowb = mrow + mi * 16 + quad * 4;
        const int bb = rowb >> 12;
        const int nl = rowb & 4095;
        const size_t base = (((size_t)bb * 512 + col) << 12) + nl;
        const float4 rv = *(const float4*)&resid[base];
        float4 ov;
        ov.x = rv.x + acc[mi][ni][0] + bvv;
        ov.y = rv.y + acc[mi][ni][1] + bvv;
        ov.z = rv.z + acc[mi][ni][2] + bvv;
        ov.w = rv.w + acc[mi][ni][3] + bvv;
        *(float4*)&C[base] = ov;
      }
    }
  } else if constexpr (EPI == 3) {  // QKV, z picks weight/bias/out; z==2 V^T
    const float* bz = p3.bias[zb];
    const float bsc = p3.bs[zb];
    ushort_t* O = p3.out[zb];
    if (zb < 2) {
#pragma unroll
      for (int ni = 0; ni < NI; ++ni) {
        const int col = ncol + ni * 16 + r16;
        const float bvv = bz[col] * bsc;
#pragma unroll
        for (int mi = 0; mi < MI; ++mi) {
          const int rowb = mrow + mi * 16 + quad * 4;
#pragma unroll
          for (int rr = 0; rr < 4; ++rr)
            O[(size_t)(rowb + rr) * 512 + col] = f2bf(acc[mi][ni][rr] + bvv);
        }
      }
    } else {
#pragma unroll
      for (int ni = 0; ni < NI; ++ni) {
        const int col = ncol + ni * 16 + r16;
        const float bvv = bz[col];
#pragma unroll
        for (int mi = 0; mi < MI; ++mi) {
          const int rowb = mrow + mi * 16 + quad * 4;
          const int bb = rowb >> 12;
          const int nn = rowb & 4095;
          ushort4 pk;
          pk.x = f2bf(acc[mi][ni][0] + bvv);
          pk.y = f2bf(acc[mi][ni][1] + bvv);
          pk.z = f2bf(acc[mi][ni][2] + bvv);
          pk.w = f2bf(acc[mi][ni][3] + bvv);
          *(ushort4*)&O[(((size_t)bb * 512 + col) << 12) + nn] = pk;
        }
      }
    }
  }
}

// ---------------- 8-wave deep-pipelined NT GEMM (256 x BN, counted vmcnt) ----
// 4 rotating half-K (32) slots per operand; 3 half-tiles in flight; raw
// s_barrier + s_waitcnt vmcnt(2L) (never 0 in-loop); setprio around MFMA.
// EPI 4: scores -> exp(acc) bf16 + atomic per-row sum into lbuf[z*4096+row].
// EPI 5: PV -> acc / lbuf[z*4096+row], bf16 out.
template <int BN, int EPI>
__global__ __launch_bounds__(512) void gemm8_nt_k(
    const ushort_t* __restrict__ A, int lda,
    const ushort_t* __restrict__ Bm, int ldb,
    void* __restrict__ Cout, int ldc, int K,
    size_t azs, size_t bzs, size_t czs,
    float* __restrict__ lbuf) {
  constexpr int WGN = BN / 64;       // waves along N: 4 (BN=256) or 2 (BN=128)
  constexpr int WGM = 8 / WGN;       // waves along M: 2 or 4
  constexpr int WTM = 256 / WGM;     // 128 or 64
  constexpr int WTN = BN / WGN;      // 64
  constexpr int MI = WTM / 16;       // 8 or 4
  constexpr int NI = WTN / 16;       // 4
  constexpr int ASZ = 256 * 32;      // ushorts per A half-slot (16KB)
  constexpr int BSZ = BN * 32;       // ushorts per B half-slot
  constexpr int BLD = BN / 128;      // B gload_lds per thread per phase (2 or 1)
  constexpr int VMC = (2 + BLD) * 2; // counted vmcnt: 2 stage-groups in flight

  extern __shared__ ushort_t lds8[];
  const int tid = threadIdx.x;
  const int lane = tid & 63;
  const int wid = tid >> 6;
  const int quad = lane >> 4;
  const int r16 = lane & 15;
  const int wm = wid / WGN, wn = wid % WGN;
  const int m0 = blockIdx.y * 256;
  const int n0 = blockIdx.x * BN;
  const int zb = blockIdx.z;

  A += azs * zb;
  Bm += bzs * zb;

  const int NPH = K >> 5;  // half-K phases

  f32x4 acc[MI][NI] = {};

  // stage half-phase ph: source clamped, slot rotation unclamped (ph & 3).
  auto stage = [&](int ph) {
    const int php = ph < NPH ? ph : NPH - 1;
    const int kt = (php >> 1) << 6;
    const int kf = php & 1;
    const int slot = ph & 3;
    ushort_t* As = lds8 + slot * ASZ;
    ushort_t* Bs = lds8 + 4 * ASZ + slot * BSZ;
#pragma unroll
    for (int r = 0; r < 2; ++r) {
      const int s = r * 512 + tid;
      const int row = s >> 2, c = s & 3;
      const int koff = kf * 32 + ((c ^ hswz(row)) << 3);
      async16(&As[s << 3], A + (size_t)(m0 + row) * lda + kt + koff);
    }
#pragma unroll
    for (int r = 0; r < BLD; ++r) {
      const int s = r * 512 + tid;
      const int row = s >> 2, c = s & 3;
      const int koff = kf * 32 + ((c ^ hswz(row)) << 3);
      async16(&Bs[s << 3], Bm + (size_t)(n0 + row) * ldb + kt + koff);
    }
  };

  stage(0); stage(1); stage(2);  // 3 half-tiles in flight

#pragma unroll 4
  for (int phi = 0; phi < NPH; ++phi) {
    // oldest half-tile (slot phi&3) complete; 2 stage-groups stay in flight
    asm volatile("s_waitcnt vmcnt(%0)" :: "i"(VMC) : "memory");
    __builtin_amdgcn_s_barrier();
    stage(phi + 3);  // into slot consumed at phase phi-1 (safe past barrier)

    const int slot = phi & 3;
    const ushort_t* As = lds8 + slot * ASZ;
    const ushort_t* Bs = lds8 + 4 * ASZ + slot * BSZ;
    bf16x8 af[MI], bfr[NI];
#pragma unroll
    for (int mi = 0; mi < MI; ++mi) {
      const int lr = wm * WTM + mi * 16 + r16;
      const int cc = quad ^ hswz(lr);
      af[mi] = *reinterpret_cast<const bf16x8*>(&As[((lr << 2) | cc) << 3]);
    }
#pragma unroll
    for (int ni = 0; ni < NI; ++ni) {
      const int lr = wn * WTN + ni * 16 + r16;
      const int cc = quad ^ hswz(lr);
      bfr[ni] = *reinterpret_cast<const bf16x8*>(&Bs[((lr << 2) | cc) << 3]);
    }
    __builtin_amdgcn_s_setprio(1);
#pragma unroll
    for (int mi = 0; mi < MI; ++mi)
#pragma unroll
      for (int ni = 0; ni < NI; ++ni)
        acc[mi][ni] = __builtin_amdgcn_mfma_f32_16x16x32_bf16(
            af[mi], bfr[ni], acc[mi][ni], 0, 0, 0);
    __builtin_amdgcn_s_setprio(0);
    // my ds_reads must be complete before I signal the next barrier
    // (next phase overwrites this slot's predecessor; keeps reuse race-free)
    asm volatile("s_waitcnt lgkmcnt(0)" ::: "memory");
  }

  const int mrow = m0 + wm * WTM;
  const int ncol = n0 + wn * WTN;
  if constexpr (EPI == 4) {  // scores: exp + bf16 + atomic row sum
    ushort_t* C = (ushort_t*)Cout + czs * zb;
    float* Lz = lbuf + (size_t)zb * 4096;
#pragma unroll
    for (int mi = 0; mi < MI; ++mi) {
#pragma unroll
      for (int rr = 0; rr < 4; ++rr) {
        const int row = mrow + mi * 16 + quad * 4 + rr;
        float ps = 0.f;
#pragma unroll
        for (int ni = 0; ni < NI; ++ni) {
          const int col = ncol + ni * 16 + r16;
          const ushort_t ub = f2bf(__expf(acc[mi][ni][rr]));
          C[(size_t)row * ldc + col] = ub;
          ps += bf2f(ub);  // sum the ROUNDED values so l matches PV's MFMA sum
        }
#pragma unroll
        for (int o = 1; o < 16; o <<= 1) ps += __shfl_xor(ps, o, 64);
        if (r16 == 0) atomicAdd(&Lz[row], ps);
      }
    }
  } else {  // EPI == 5: PV, divide by row sum, bf16 out
    ushort_t* C = (ushort_t*)Cout + czs * zb;
    const float* Lz = lbuf + (size_t)zb * 4096;
#pragma unroll
    for (int mi = 0; mi < MI; ++mi) {
#pragma unroll
      for (int rr = 0; rr < 4; ++rr) {
        const int row = mrow + mi * 16 + quad * 4 + rr;
        const float inv = 1.f / Lz[row];
#pragma unroll
        for (int ni = 0; ni < NI; ++ni) {
          const int col = ncol + ni * 16 + r16;
          C[(size_t)row * ldc + col] = f2bf(acc[mi][ni][rr] * inv);
        }
      }
    }
  }
}

extern "C" void kernel_launch(void* const* d_in, const int* in_sizes, int n_in,
                              void* d_out, int out_size, void* d_ws, size_t ws_size,
                              hipStream_t stream) {
  const float* x  = (const float*)d_in[0];
  const float* gs = (const float*)d_in[1];
  const float* gb = (const float*)d_in[2];
  const float* wq = (const float*)d_in[3];
  const float* bq = (const float*)d_in[4];
  const float* wk = (const float*)d_in[5];
  const float* bk = (const float*)d_in[6];
  const float* wv = (const float*)d_in[7];
  const float* bv = (const float*)d_in[8];
  const float* wo = (const float*)d_in[9];
  const float* bo = (const float*)d_in[10];
  float* out = (float*)d_out;

  const size_t HNC = (size_t)4 * 4096 * 512;
  char* w = (char*)d_ws;
  float* stats  = (float*)w;    w += 4096;
  float* Ls     = (float*)w;    w += (size_t)4 * 4096 * 4;  // exp row sums
  ushort_t* wb  = (ushort_t*)w; w += (size_t)4 * 262144 * 2;
  ushort_t* h   = (ushort_t*)w; w += HNC * 2;  // GN out; reused as O
  ushort_t* q   = (ushort_t*)w; w += HNC * 2;
  ushort_t* kk  = (ushort_t*)w; w += HNC * 2;
  ushort_t* vt  = (ushort_t*)w; w += HNC * 2;  // V transposed [B,C,N]
  ushort_t* Se  = (ushort_t*)w; w += (size_t)4 * 4096 * 4096 * 2;  // exp(S) bf16

  const float sc = 0.044194173824159216f;  // 512^-0.5, folded into wq/bq

  static bool attr_done = false;
  if (!attr_done) {
    (void)hipFuncSetAttribute((const void*)gemm8_nt_k<256, 4>,
                              hipFuncAttributeMaxDynamicSharedMemorySize, 131072);
    (void)hipFuncSetAttribute((const void*)gemm8_nt_k<128, 5>,
                              hipFuncAttributeMaxDynamicSharedMemorySize, 131072);
    attr_done = true;
  }

  gn_stats_k<<<128, 256, 0, stream>>>(x, stats);
  gn_apply_k<<<8192, 256, 0, stream>>>(x, stats, gs, gb, h);
  Ptr4 wsrc;
  wsrc.src[0] = wq; wsrc.src[1] = wk; wsrc.src[2] = wv; wsrc.src[3] = wo;
  wsrc.wsc[0] = sc; wsrc.wsc[1] = 1.f; wsrc.wsc[2] = 1.f; wsrc.wsc[3] = 1.f;
  cvt_all_k<<<4096, 256, 0, stream>>>(wsrc, wb);
  hipMemsetAsync(Ls, 0, (size_t)4 * 4096 * 4, stream);

  Ptr3 qkv;
  qkv.bias[0] = bq; qkv.bias[1] = bk; qkv.bias[2] = bv;
  qkv.out[0] = q; qkv.out[1] = kk; qkv.out[2] = vt;
  qkv.bs[0] = sc; qkv.bs[1] = 1.f; qkv.bs[2] = 1.f;
  gemm_nt_k<128, 128, 32, 3><<<dim3(4, 128, 3), 256, 0, stream>>>(
      h, 512, wb, 512, nullptr, 0, nullptr, nullptr, 1.f, 512,
      0, 262144, 0, qkv, nullptr);

  // Se[z] = exp(q k^T) bf16, plus atomic row sums into Ls (deep-pipelined)
  gemm8_nt_k<256, 4><<<dim3(16, 16, 4), 512, 131072, stream>>>(
      q, 512, kk, 512, Se, 4096, 512,
      (size_t)4096 * 512, (size_t)4096 * 512, (size_t)4096 * 4096, Ls);
  // O[z] = (Se V) / l, bf16 into h (deep-pipelined)
  gemm8_nt_k<128, 5><<<dim3(4, 16, 4), 512, 98304, stream>>>(
      Se, 4096, vt, 4096, h, 512, 4096,
      (size_t)4096 * 4096, (size_t)512 * 4096, (size_t)4096 * 512, Ls);

  // out = x + O @ wo^T + bo, transposed back to [B,C,H,W]
  Ptr3 e0{};
  gemm_nt_k<128, 128, 32, 2><<<dim3(4, 128, 1), 256, 0, stream>>>(
      h, 512, wb + (size_t)3 * 262144, 512, out, 512, bo, x, 1.f, 512,
      0, 0, 0, e0, nullptr);
}

// Round 2
// 394.748 us; speedup vs baseline: 1.1746x; 1.1746x over previous
//
#include <hip/hip_runtime.h>
#include <cstdint>
#include <cstddef>

typedef unsigned short ushort_t;
typedef __attribute__((ext_vector_type(8))) __bf16 bf16x8;
typedef __attribute__((ext_vector_type(4))) float f32x4;

#define DEVINL __device__ __forceinline__

DEVINL ushort_t f2bf(float f) {
  union { __bf16 b; ushort_t u; } v;
  v.b = (__bf16)f;
  return v.u;
}
DEVINL float bf2f(ushort_t u) {
  union { unsigned u; float f; } v; v.u = ((unsigned)u) << 16;
  return v.f;
}

DEVINL float wred_sum(float x) {
#pragma unroll
  for (int o = 32; o > 0; o >>= 1) x += __shfl_xor(x, o, 64);
  return x;
}

// async global->LDS, 16B per lane (global_load_lds_dwordx4)
DEVINL void async16(ushort_t* lds, const ushort_t* g) {
  __builtin_amdgcn_global_load_lds(
      (__attribute__((address_space(1))) const unsigned int*)g,
      (__attribute__((address_space(3))) unsigned int*)lds, 16, 0, 0);
}

template <int CPR>
DEVINL int fswz(int r) {
  if constexpr (CPR == 4) return (r >> 2) & 3;
  else return r & 7;  // CPR==8
}

// ---------------- GroupNorm ----------------
__global__ __launch_bounds__(256) void gn_stats_k(const float* __restrict__ x,
                                                  float* __restrict__ stats) {
  const int bg = blockIdx.x;
  const float4* base = (const float4*)(x + ((size_t)bg << 16));
  float s = 0.f, q = 0.f;
  for (int i = threadIdx.x; i < 16384; i += 256) {
    float4 f = base[i];
    s += f.x + f.y + f.z + f.w;
    q += f.x * f.x + f.y * f.y + f.z * f.z + f.w * f.w;
  }
  s = wred_sum(s);
  q = wred_sum(q);
  __shared__ float rs[4], rq[4];
  const int lane = threadIdx.x & 63, wid = threadIdx.x >> 6;
  if (lane == 0) { rs[wid] = s; rq[wid] = q; }
  __syncthreads();
  if (threadIdx.x == 0) {
    float S = rs[0] + rs[1] + rs[2] + rs[3];
    float Q = rq[0] + rq[1] + rq[2] + rq[3];
    float mean = S * (1.f / 65536.f);
    float var = Q * (1.f / 65536.f) - mean * mean;
    stats[2 * bg] = mean;
    stats[2 * bg + 1] = rsqrtf(var + 1e-5f);
  }
}

__global__ __launch_bounds__(256) void gn_apply_k(const float* __restrict__ x,
                                                  const float* __restrict__ stats,
                                                  const float* __restrict__ gs,
                                                  const float* __restrict__ gb,
                                                  ushort_t* __restrict__ h) {
  __shared__ ushort_t tile[32][33];
  const int bid = blockIdx.x;
  const int b = bid >> 11;
  const int r = bid & 2047;
  const int ct = r >> 7, nt = r & 127;
  const int c0 = ct << 5, n0 = nt << 5;
  const int tx = threadIdx.x & 31, ty = threadIdx.x >> 5;
#pragma unroll
  for (int i = 0; i < 4; ++i) {
    const int c = c0 + ty + i * 8;
    const float mean = stats[2 * (b * 32 + (c >> 4))];
    const float rstd = stats[2 * (b * 32 + (c >> 4)) + 1];
    const float xv = x[(((size_t)b * 512 + c) << 12) + n0 + tx];
    tile[ty + i * 8][tx] = f2bf((xv - mean) * rstd * gs[c] + gb[c]);
  }
  __syncthreads();
#pragma unroll
  for (int i = 0; i < 4; ++i) {
    const int n = n0 + ty + i * 8;
    h[(((size_t)b << 12) + n) * 512 + c0 + tx] = tile[tx][ty + i * 8];
  }
}

// fp32 -> bf16 convert with per-matrix scale (sc folded into wq)
struct Ptr4 { const float* src[4]; float wsc[4]; };
__global__ __launch_bounds__(256) void cvt_all_k(Ptr4 s, ushort_t* __restrict__ dst) {
  const int i = blockIdx.x * 256 + threadIdx.x;
  const int m = i >> 18;
  dst[i] = f2bf(s.src[m][i & 262143] * s.wsc[m]);
}

// ---------------- NT GEMM (128x128, 2-barrier): C[M,N] = A[M,K] * B[N,K]^T ----
// EPI 2: fp32 transposed out + resid + bias (final projection).
// EPI 3: QKV fused, z picks weight/bias/out; z==2 (V) writes transposed [C][N].
struct Ptr3 { const float* bias[3]; ushort_t* out[3]; float bs[3]; };

template <int BM, int BN, int BK, int EPI>
__global__ __launch_bounds__(256) void gemm_nt_k(
    const ushort_t* __restrict__ A, int lda, const ushort_t* __restrict__ Bm, int ldb,
    void* __restrict__ Cout, int ldc, const float* __restrict__ bias,
    const float* __restrict__ resid, float scale, int K,
    size_t azs, size_t bzs, size_t czs, Ptr3 p3, float* __restrict__ lbuf) {
  constexpr int CPR = BK / 8;
  constexpr int WTM = BM / 2, WTN = BN / 2;
  constexpr int MI = WTM / 16, NI = WTN / 16;
  constexpr int AR = (BM * CPR) / 256;
  constexpr int BR = (BN * CPR) / 256;
  __shared__ ushort_t Als[BM * BK];
  __shared__ ushort_t Bls[BN * BK];
  const int tid = threadIdx.x;
  const int lane = tid & 63;
  const int wid = tid >> 6;
  const int quad = lane >> 4;
  const int r16 = lane & 15;
  const int wm = wid >> 1, wn = wid & 1;
  const int m0 = blockIdx.y * BM;
  const int n0 = blockIdx.x * BN;
  const int zb = blockIdx.z;

  A += azs * zb;
  Bm += bzs * zb;

  f32x4 acc[MI][NI] = {};

  for (int kt = 0; kt < K; kt += BK) {
#pragma unroll
    for (int r = 0; r < AR; ++r) {
      const int s = r * 256 + tid;
      const int row = s / CPR;
      const int q = (s % CPR) ^ fswz<CPR>(row);
      async16(&Als[s << 3], A + (size_t)(m0 + row) * lda + kt + (q << 3));
    }
#pragma unroll
    for (int r = 0; r < BR; ++r) {
      const int s = r * 256 + tid;
      const int row = s / CPR;
      const int q = (s % CPR) ^ fswz<CPR>(row);
      async16(&Bls[s << 3], Bm + (size_t)(n0 + row) * ldb + kt + (q << 3));
    }
    __syncthreads();
#pragma unroll
    for (int kf = 0; kf < BK / 32; ++kf) {
      bf16x8 af[MI], bfr[NI];
#pragma unroll
      for (int mi = 0; mi < MI; ++mi) {
        const int lr = wm * WTM + mi * 16 + r16;
        const int ch = kf * 4 + quad;
        af[mi] = *reinterpret_cast<const bf16x8*>(
            &Als[(lr * CPR + (ch ^ fswz<CPR>(lr))) << 3]);
      }
#pragma unroll
      for (int ni = 0; ni < NI; ++ni) {
        const int lr = wn * WTN + ni * 16 + r16;
        const int ch = kf * 4 + quad;
        bfr[ni] = *reinterpret_cast<const bf16x8*>(
            &Bls[(lr * CPR + (ch ^ fswz<CPR>(lr))) << 3]);
      }
#pragma unroll
      for (int mi = 0; mi < MI; ++mi)
#pragma unroll
        for (int ni = 0; ni < NI; ++ni)
          acc[mi][ni] = __builtin_amdgcn_mfma_f32_16x16x32_bf16(
              af[mi], bfr[ni], acc[mi][ni], 0, 0, 0);
    }
    __syncthreads();
  }

  const int mrow = m0 + wm * WTM;
  const int ncol = n0 + wn * WTN;
  if constexpr (EPI == 2) {  // final: fp32 transposed out + resid + bias
    float* C = (float*)Cout;
#pragma unroll
    for (int ni = 0; ni < NI; ++ni) {
      const int col = ncol + ni * 16 + r16;
      const float bvv = bias[col];
#pragma unroll
      for (int mi = 0; mi < MI; ++mi) {
        const int rowb = mrow + mi * 16 + quad * 4;
        const int bb = rowb >> 12;
        const int nl = rowb & 4095;
        const size_t base = (((size_t)bb * 512 + col) << 12) + nl;
        const float4 rv = *(const float4*)&resid[base];
        float4 ov;
        ov.x = rv.x + acc[mi][ni][0] + bvv;
        ov.y = rv.y + acc[mi][ni][1] + bvv;
        ov.z = rv.z + acc[mi][ni][2] + bvv;
        ov.w = rv.w + acc[mi][ni][3] + bvv;
        *(float4*)&C[base] = ov;
      }
    }
  } else if constexpr (EPI == 3) {  // QKV, z picks weight/bias/out; z==2 V^T
    const float* bz = p3.bias[zb];
    const float bsc = p3.bs[zb];
    ushort_t* O = p3.out[zb];
    if (zb < 2) {
#pragma unroll
      for (int ni = 0; ni < NI; ++ni) {
        const int col = ncol + ni * 16 + r16;
        const float bvv = bz[col] * bsc;
#pragma unroll
        for (int mi = 0; mi < MI; ++mi) {
          const int rowb = mrow + mi * 16 + quad * 4;
#pragma unroll
          for (int rr = 0; rr < 4; ++rr)
            O[(size_t)(rowb + rr) * 512 + col] = f2bf(acc[mi][ni][rr] + bvv);
        }
      }
    } else {
#pragma unroll
      for (int ni = 0; ni < NI; ++ni) {
        const int col = ncol + ni * 16 + r16;
        const float bvv = bz[col];
#pragma unroll
        for (int mi = 0; mi < MI; ++mi) {
          const int rowb = mrow + mi * 16 + quad * 4;
          const int bb = rowb >> 12;
          const int nn = rowb & 4095;
          ushort4 pk;
          pk.x = f2bf(acc[mi][ni][0] + bvv);
          pk.y = f2bf(acc[mi][ni][1] + bvv);
          pk.z = f2bf(acc[mi][ni][2] + bvv);
          pk.w = f2bf(acc[mi][ni][3] + bvv);
          *(ushort4*)&O[(((size_t)bb * 512 + col) << 12) + nn] = pk;
        }
      }
    }
  }
}

// ------- 8-wave, C-quadrant 4-phase pipelined NT GEMM (m201-style) -------
// BK=64, double-buffered LDS; per K-tile: 4 phases, each stages a group of
// next-tile loads; ONE counted vmcnt per K-tile (phase 0) + barrier makes
// the whole tile's loads globally visible. Quadrant walk (0,0)->(0,1)->
// (1,1)->(1,0) reuses held A/B fragments (only the changed half reloads).
// EPI 4: scores -> exp(acc) bf16 + atomic per-row sum into lbuf[z*4096+row].
// EPI 5: PV -> acc / lbuf[z*4096+row], bf16 out.
template <int BM, int BN, int WGM, int WGN, int EPI>
__global__ __launch_bounds__(512, 2) void gemm8p_k(
    const ushort_t* __restrict__ A, int lda,
    const ushort_t* __restrict__ Bm, int ldb,
    void* __restrict__ Cout, int ldc, int K,
    size_t azs, size_t bzs, size_t czs, float* __restrict__ lbuf) {
  constexpr int WTM = BM / WGM, WTN = BN / WGN;
  constexpr int MI = WTM / 16, NI = WTN / 16;
  constexpr int MH = MI / 2, NH = NI / 2;
  constexpr int ALD = BM / 64;        // A gload_lds per thread per K-tile
  constexpr int BLD = BN / 64;
  constexpr int TOT = ALD + BLD;
  constexpr int VMC = TOT / 4;        // loads staged in phase-0 group
  constexpr int AHALF = BM * 64;      // ushorts per A buffer
  constexpr int HALF = (BM + BN) * 64;

  extern __shared__ ushort_t lds8[];
  const int tid = threadIdx.x;
  const int lane = tid & 63;
  const int quad = lane >> 4;
  const int r16 = lane & 15;
  const int wid = tid >> 6;
  const int wm = wid / WGN, wn = wid % WGN;

  // XCD-clustered block swizzle (HW runs flat%8 on XCD flat%8)
  int bx, by, bz;
  {
    const int flat = blockIdx.x + (EPI == 4 ? 16 : 4) * (blockIdx.y + 16 * blockIdx.z);
    if constexpr (EPI == 4) {  // grid 16x16x4: 4x4 tile-chunks per XCD
      const int xcd = flat & 7, s = flat >> 3;
      const int w = s & 31, half = w >> 4, idx = w & 15;
      bx = (xcd & 3) * 4 + (idx & 3);
      by = ((xcd >> 2) + 2 * half) * 4 + (idx >> 2);
      bz = s >> 5;
    } else {                   // grid 4x16x4: x-siblings (shared Se panel) per XCD
      const int xcd = flat & 7, s = flat >> 3;
      bx = s & 3;
      const int yz = xcd + (s >> 2) * 8;
      by = yz & 15; bz = yz >> 4;
    }
  }
  const int m0 = by * BM, n0 = bx * BN, zb = bz;
  A += azs * zb;
  Bm += bzs * zb;
  const int NT = K >> 6;

  // per-thread stage sources (tile col offset added per stage) + LDS dests
  const ushort_t* src[TOT];
  ushort_t* dst[TOT];
#pragma unroll
  for (int l = 0; l < TOT; ++l) {
    const bool isA = l < ALD;
    const int li = isA ? l : l - ALD;
    const int s = li * 512 + tid;
    const int row = s >> 3;
    const int q = (s & 7) ^ (row & 7);  // proven CPR=8 chunk swizzle
    src[l] = (isA ? A + (size_t)(m0 + row) * lda
                  : Bm + (size_t)(n0 + row) * ldb) + (q << 3);
    dst[l] = lds8 + (isA ? 0 : AHALF) + (s << 3);
  }

  f32x4 acc[MI][NI] = {};

  // prologue: stage tile 0 into buffer 0
#pragma unroll
  for (int l = 0; l < TOT; ++l) async16(dst[l], src[l]);

  bf16x8 afq[MH][2], bfq[NH][2];

#pragma unroll 2
  for (int t = 0; t < NT; ++t) {
    const int nbuf = (t + 1) & 1;
    const ushort_t* Ab = lds8 + (t & 1) * HALF;
    const ushort_t* Bb = Ab + AHALF;
    // clamped source (dummy re-stage on last tile keeps the vmcnt ledger exact)
    const int koff = ((t + 1 < NT) ? t + 1 : NT - 1) << 6;

#define STAGEG(G)                                                              \
    { constexpr int S_ = ((G) * TOT) / 4, E_ = (((G) + 1) * TOT) / 4;          \
      _Pragma("unroll")                                                        \
      for (int l = S_; l < E_; ++l) async16(dst[l] + nbuf * HALF, src[l] + koff); }

#define LOADA(MHh)                                                             \
    _Pragma("unroll") for (int i = 0; i < MH; ++i)                             \
    _Pragma("unroll") for (int kf = 0; kf < 2; ++kf) {                         \
      const int lr = wm * WTM + ((MHh) * MH + i) * 16 + r16;                   \
      const int cc = (kf * 4 + quad) ^ (lr & 7);                               \
      afq[i][kf] = *reinterpret_cast<const bf16x8*>(&Ab[lr * 64 + cc * 8]); }

#define LOADB(NHh)                                                             \
    _Pragma("unroll") for (int j = 0; j < NH; ++j)                             \
    _Pragma("unroll") for (int kf = 0; kf < 2; ++kf) {                         \
      const int lr = wn * WTN + ((NHh) * NH + j) * 16 + r16;                   \
      const int cc = (kf * 4 + quad) ^ (lr & 7);                               \
      bfq[j][kf] = *reinterpret_cast<const bf16x8*>(&Bb[lr * 64 + cc * 8]); }

#define MMAQ(MHh, NHh)                                                         \
    __builtin_amdgcn_s_setprio(1);                                             \
    _Pragma("unroll") for (int i = 0; i < MH; ++i)                             \
    _Pragma("unroll") for (int j = 0; j < NH; ++j)                             \
    _Pragma("unroll") for (int kf = 0; kf < 2; ++kf)                           \
      acc[(MHh) * MH + i][(NHh) * NH + j] =                                    \
          __builtin_amdgcn_mfma_f32_16x16x32_bf16(                             \
              afq[i][kf], bfq[j][kf], acc[(MHh) * MH + i][(NHh) * NH + j],     \
              0, 0, 0);                                                        \
    __builtin_amdgcn_s_setprio(0);

    // phase 0 : quadrant (0,0) — the one gated phase per K-tile
    STAGEG(0)
    asm volatile("s_waitcnt vmcnt(%0)" :: "i"(VMC) : "memory");
    __builtin_amdgcn_s_barrier();
    __builtin_amdgcn_sched_barrier(0);
    LOADA(0)
    LOADB(0)
    MMAQ(0, 0)
    __builtin_amdgcn_sched_barrier(0);
    __builtin_amdgcn_s_barrier();
    // phase 1 : (0,1) — keep A frags, reload B half 1
    STAGEG(1)
    LOADB(1)
    MMAQ(0, 1)
    __builtin_amdgcn_sched_barrier(0);
    __builtin_amdgcn_s_barrier();
    // phase 2 : (1,1) — keep B frags, reload A half 1
    STAGEG(2)
    LOADA(1)
    MMAQ(1, 1)
    __builtin_amdgcn_sched_barrier(0);
    __builtin_amdgcn_s_barrier();
    // phase 3 : (1,0) — keep A frags, reload B half 0
    STAGEG(3)
    LOADB(0)
    MMAQ(1, 0)
    __builtin_amdgcn_sched_barrier(0);
    __builtin_amdgcn_s_barrier();
#undef STAGEG
#undef LOADA
#undef LOADB
#undef MMAQ
  }

  const int mrow = m0 + wm * WTM;
  const int ncol = n0 + wn * WTN;
  if constexpr (EPI == 4) {  // scores: exp + bf16 + atomic row sum
    ushort_t* C = (ushort_t*)Cout + czs * zb;
    float* Lz = lbuf + (size_t)zb * 4096;
#pragma unroll
    for (int mi = 0; mi < MI; ++mi) {
#pragma unroll
      for (int rr = 0; rr < 4; ++rr) {
        const int row = mrow + mi * 16 + quad * 4 + rr;
        float ps = 0.f;
#pragma unroll
        for (int ni = 0; ni < NI; ++ni) {
          const int col = ncol + ni * 16 + r16;
          const ushort_t ub = f2bf(__expf(acc[mi][ni][rr]));
          C[(size_t)row * ldc + col] = ub;
          ps += bf2f(ub);  // sum the ROUNDED values so l matches PV's MFMA sum
        }
#pragma unroll
        for (int o = 1; o < 16; o <<= 1) ps += __shfl_xor(ps, o, 64);
        if (r16 == 0) atomicAdd(&Lz[row], ps);
      }
    }
  } else {  // EPI == 5: PV, divide by row sum, bf16 out
    ushort_t* C = (ushort_t*)Cout + czs * zb;
    const float* Lz = lbuf + (size_t)zb * 4096;
#pragma unroll
    for (int mi = 0; mi < MI; ++mi) {
#pragma unroll
      for (int rr = 0; rr < 4; ++rr) {
        const int row = mrow + mi * 16 + quad * 4 + rr;
        const float inv = 1.f / Lz[row];
#pragma unroll
        for (int ni = 0; ni < NI; ++ni) {
          const int col = ncol + ni * 16 + r16;
          C[(size_t)row * ldc + col] = f2bf(acc[mi][ni][rr] * inv);
        }
      }
    }
  }
}

extern "C" void kernel_launch(void* const* d_in, const int* in_sizes, int n_in,
                              void* d_out, int out_size, void* d_ws, size_t ws_size,
                              hipStream_t stream) {
  const float* x  = (const float*)d_in[0];
  const float* gs = (const float*)d_in[1];
  const float* gb = (const float*)d_in[2];
  const float* wq = (const float*)d_in[3];
  const float* bq = (const float*)d_in[4];
  const float* wk = (const float*)d_in[5];
  const float* bk = (const float*)d_in[6];
  const float* wv = (const float*)d_in[7];
  const float* bv = (const float*)d_in[8];
  const float* wo = (const float*)d_in[9];
  const float* bo = (const float*)d_in[10];
  float* out = (float*)d_out;

  const size_t HNC = (size_t)4 * 4096 * 512;
  char* w = (char*)d_ws;
  float* stats  = (float*)w;    w += 4096;
  float* Ls     = (float*)w;    w += (size_t)4 * 4096 * 4;  // exp row sums
  ushort_t* wb  = (ushort_t*)w; w += (size_t)4 * 262144 * 2;
  ushort_t* h   = (ushort_t*)w; w += HNC * 2;  // GN out; reused as O
  ushort_t* q   = (ushort_t*)w; w += HNC * 2;
  ushort_t* kk  = (ushort_t*)w; w += HNC * 2;
  ushort_t* vt  = (ushort_t*)w; w += HNC * 2;  // V transposed [B,C,N]
  ushort_t* Se  = (ushort_t*)w; w += (size_t)4 * 4096 * 4096 * 2;  // exp(S) bf16

  const float sc = 0.044194173824159216f;  // 512^-0.5, folded into wq/bq

  static bool attr_done = false;
  if (!attr_done) {
    (void)hipFuncSetAttribute((const void*)gemm8p_k<256, 256, 2, 4, 4>,
                              hipFuncAttributeMaxDynamicSharedMemorySize, 131072);
    (void)hipFuncSetAttribute((const void*)gemm8p_k<256, 128, 4, 2, 5>,
                              hipFuncAttributeMaxDynamicSharedMemorySize, 98304);
    attr_done = true;
  }

  gn_stats_k<<<128, 256, 0, stream>>>(x, stats);
  gn_apply_k<<<8192, 256, 0, stream>>>(x, stats, gs, gb, h);
  Ptr4 wsrc;
  wsrc.src[0] = wq; wsrc.src[1] = wk; wsrc.src[2] = wv; wsrc.src[3] = wo;
  wsrc.wsc[0] = sc; wsrc.wsc[1] = 1.f; wsrc.wsc[2] = 1.f; wsrc.wsc[3] = 1.f;
  cvt_all_k<<<4096, 256, 0, stream>>>(wsrc, wb);
  hipMemsetAsync(Ls, 0, (size_t)4 * 4096 * 4, stream);

  Ptr3 qkv;
  qkv.bias[0] = bq; qkv.bias[1] = bk; qkv.bias[2] = bv;
  qkv.out[0] = q; qkv.out[1] = kk; qkv.out[2] = vt;
  qkv.bs[0] = sc; qkv.bs[1] = 1.f; qkv.bs[2] = 1.f;
  gemm_nt_k<128, 128, 32, 3><<<dim3(4, 128, 3), 256, 0, stream>>>(
      h, 512, wb, 512, nullptr, 0, nullptr, nullptr, 1.f, 512,
      0, 262144, 0, qkv, nullptr);

  // Se[z] = exp(q k^T) bf16 + atomic row sums (256x256, quadrant pipeline)
  gemm8p_k<256, 256, 2, 4, 4><<<dim3(16, 16, 4), 512, 131072, stream>>>(
      q, 512, kk, 512, Se, 4096, 512,
      (size_t)4096 * 512, (size_t)4096 * 512, (size_t)4096 * 4096, Ls);
  // O[z] = (Se V) / l, bf16 into h (256x128, quadrant pipeline)
  gemm8p_k<256, 128, 4, 2, 5><<<dim3(4, 16, 4), 512, 98304, stream>>>(
      Se, 4096, vt, 4096, h, 512, 4096,
      (size_t)4096 * 4096, (size_t)512 * 4096, (size_t)4096 * 512, Ls);

  // out = x + O @ wo^T + bo, transposed back to [B,C,H,W]
  Ptr3 e0{};
  gemm_nt_k<128, 128, 32, 2><<<dim3(4, 128, 1), 256, 0, stream>>>(
      h, 512, wb + (size_t)3 * 262144, 512, out, 512, bo, x, 1.f, 512,
      0, 0, 0, e0, nullptr);
}

// Round 3
// 394.369 us; speedup vs baseline: 1.1757x; 1.0010x over previous
//
#include <hip/hip_runtime.h>
#include <cstdint>
#include <cstddef>

typedef unsigned short ushort_t;
typedef __attribute__((ext_vector_type(8))) __bf16 bf16x8;
typedef __attribute__((ext_vector_type(4))) float f32x4;

#define DEVINL __device__ __forceinline__

DEVINL ushort_t f2bf(float f) {
  union { __bf16 b; ushort_t u; } v;
  v.b = (__bf16)f;
  return v.u;
}
DEVINL float bf2f(ushort_t u) {
  union { unsigned u; float f; } v; v.u = ((unsigned)u) << 16;
  return v.f;
}

DEVINL float wred_sum(float x) {
#pragma unroll
  for (int o = 32; o > 0; o >>= 1) x += __shfl_xor(x, o, 64);
  return x;
}

// async global->LDS, 16B per lane (global_load_lds_dwordx4)
DEVINL void async16(ushort_t* lds, const ushort_t* g) {
  __builtin_amdgcn_global_load_lds(
      (__attribute__((address_space(1))) const unsigned int*)g,
      (__attribute__((address_space(3))) unsigned int*)lds, 16, 0, 0);
}

template <int CPR>
DEVINL int fswz(int r) {
  if constexpr (CPR == 4) return (r >> 2) & 3;
  else return r & 7;  // CPR==8
}

// ---------------- GroupNorm ----------------
__global__ __launch_bounds__(256) void gn_stats_k(const float* __restrict__ x,
                                                  float* __restrict__ stats) {
  const int bg = blockIdx.x;
  const float4* base = (const float4*)(x + ((size_t)bg << 16));
  float s = 0.f, q = 0.f;
  for (int i = threadIdx.x; i < 16384; i += 256) {
    float4 f = base[i];
    s += f.x + f.y + f.z + f.w;
    q += f.x * f.x + f.y * f.y + f.z * f.z + f.w * f.w;
  }
  s = wred_sum(s);
  q = wred_sum(q);
  __shared__ float rs[4], rq[4];
  const int lane = threadIdx.x & 63, wid = threadIdx.x >> 6;
  if (lane == 0) { rs[wid] = s; rq[wid] = q; }
  __syncthreads();
  if (threadIdx.x == 0) {
    float S = rs[0] + rs[1] + rs[2] + rs[3];
    float Q = rq[0] + rq[1] + rq[2] + rq[3];
    float mean = S * (1.f / 65536.f);
    float var = Q * (1.f / 65536.f) - mean * mean;
    stats[2 * bg] = mean;
    stats[2 * bg + 1] = rsqrtf(var + 1e-5f);
  }
}

__global__ __launch_bounds__(256) void gn_apply_k(const float* __restrict__ x,
                                                  const float* __restrict__ stats,
                                                  const float* __restrict__ gs,
                                                  const float* __restrict__ gb,
                                                  ushort_t* __restrict__ h) {
  __shared__ ushort_t tile[32][33];
  const int bid = blockIdx.x;
  const int b = bid >> 11;
  const int r = bid & 2047;
  const int ct = r >> 7, nt = r & 127;
  const int c0 = ct << 5, n0 = nt << 5;
  const int tx = threadIdx.x & 31, ty = threadIdx.x >> 5;
#pragma unroll
  for (int i = 0; i < 4; ++i) {
    const int c = c0 + ty + i * 8;
    const float mean = stats[2 * (b * 32 + (c >> 4))];
    const float rstd = stats[2 * (b * 32 + (c >> 4)) + 1];
    const float xv = x[(((size_t)b * 512 + c) << 12) + n0 + tx];
    tile[ty + i * 8][tx] = f2bf((xv - mean) * rstd * gs[c] + gb[c]);
  }
  __syncthreads();
#pragma unroll
  for (int i = 0; i < 4; ++i) {
    const int n = n0 + ty + i * 8;
    h[(((size_t)b << 12) + n) * 512 + c0 + tx] = tile[tx][ty + i * 8];
  }
}

// fp32 -> bf16 convert with per-matrix scale (sc folded into wq)
struct Ptr4 { const float* src[4]; float wsc[4]; };
__global__ __launch_bounds__(256) void cvt_all_k(Ptr4 s, ushort_t* __restrict__ dst) {
  const int i = blockIdx.x * 256 + threadIdx.x;
  const int m = i >> 18;
  dst[i] = f2bf(s.src[m][i & 262143] * s.wsc[m]);
}

// ---------------- NT GEMM (128x128, 2-barrier): C[M,N] = A[M,K] * B[N,K]^T ----
// EPI 2: fp32 transposed out + resid + bias (final projection).
// EPI 3: QKV fused, z picks weight/bias/out; z==2 (V) writes transposed [C][N].
struct Ptr3 { const float* bias[3]; ushort_t* out[3]; float bs[3]; };

template <int BM, int BN, int BK, int EPI>
__global__ __launch_bounds__(256) void gemm_nt_k(
    const ushort_t* __restrict__ A, int lda, const ushort_t* __restrict__ Bm, int ldb,
    void* __restrict__ Cout, int ldc, const float* __restrict__ bias,
    const float* __restrict__ resid, float scale, int K,
    size_t azs, size_t bzs, size_t czs, Ptr3 p3, float* __restrict__ lbuf) {
  constexpr int CPR = BK / 8;
  constexpr int WTM = BM / 2, WTN = BN / 2;
  constexpr int MI = WTM / 16, NI = WTN / 16;
  constexpr int AR = (BM * CPR) / 256;
  constexpr int BR = (BN * CPR) / 256;
  __shared__ ushort_t Als[BM * BK];
  __shared__ ushort_t Bls[BN * BK];
  const int tid = threadIdx.x;
  const int lane = tid & 63;
  const int wid = tid >> 6;
  const int quad = lane >> 4;
  const int r16 = lane & 15;
  const int wm = wid >> 1, wn = wid & 1;
  const int m0 = blockIdx.y * BM;
  const int n0 = blockIdx.x * BN;
  const int zb = blockIdx.z;

  A += azs * zb;
  Bm += bzs * zb;

  f32x4 acc[MI][NI] = {};

  for (int kt = 0; kt < K; kt += BK) {
#pragma unroll
    for (int r = 0; r < AR; ++r) {
      const int s = r * 256 + tid;
      const int row = s / CPR;
      const int q = (s % CPR) ^ fswz<CPR>(row);
      async16(&Als[s << 3], A + (size_t)(m0 + row) * lda + kt + (q << 3));
    }
#pragma unroll
    for (int r = 0; r < BR; ++r) {
      const int s = r * 256 + tid;
      const int row = s / CPR;
      const int q = (s % CPR) ^ fswz<CPR>(row);
      async16(&Bls[s << 3], Bm + (size_t)(n0 + row) * ldb + kt + (q << 3));
    }
    __syncthreads();
#pragma unroll
    for (int kf = 0; kf < BK / 32; ++kf) {
      bf16x8 af[MI], bfr[NI];
#pragma unroll
      for (int mi = 0; mi < MI; ++mi) {
        const int lr = wm * WTM + mi * 16 + r16;
        const int ch = kf * 4 + quad;
        af[mi] = *reinterpret_cast<const bf16x8*>(
            &Als[(lr * CPR + (ch ^ fswz<CPR>(lr))) << 3]);
      }
#pragma unroll
      for (int ni = 0; ni < NI; ++ni) {
        const int lr = wn * WTN + ni * 16 + r16;
        const int ch = kf * 4 + quad;
        bfr[ni] = *reinterpret_cast<const bf16x8*>(
            &Bls[(lr * CPR + (ch ^ fswz<CPR>(lr))) << 3]);
      }
#pragma unroll
      for (int mi = 0; mi < MI; ++mi)
#pragma unroll
        for (int ni = 0; ni < NI; ++ni)
          acc[mi][ni] = __builtin_amdgcn_mfma_f32_16x16x32_bf16(
              af[mi], bfr[ni], acc[mi][ni], 0, 0, 0);
    }
    __syncthreads();
  }

  const int mrow = m0 + wm * WTM;
  const int ncol = n0 + wn * WTN;
  if constexpr (EPI == 2) {  // final: fp32 transposed out + resid + bias
    float* C = (float*)Cout;
#pragma unroll
    for (int ni = 0; ni < NI; ++ni) {
      const int col = ncol + ni * 16 + r16;
      const float bvv = bias[col];
#pragma unroll
      for (int mi = 0; mi < MI; ++mi) {
        const int rowb = mrow + mi * 16 + quad * 4;
        const int bb = rowb >> 12;
        const int nl = rowb & 4095;
        const size_t base = (((size_t)bb * 512 + col) << 12) + nl;
        const float4 rv = *(const float4*)&resid[base];
        float4 ov;
        ov.x = rv.x + acc[mi][ni][0] + bvv;
        ov.y = rv.y + acc[mi][ni][1] + bvv;
        ov.z = rv.z + acc[mi][ni][2] + bvv;
        ov.w = rv.w + acc[mi][ni][3] + bvv;
        *(float4*)&C[base] = ov;
      }
    }
  } else if constexpr (EPI == 3) {  // QKV, z picks weight/bias/out; z==2 V^T
    const float* bz = p3.bias[zb];
    const float bsc = p3.bs[zb];
    ushort_t* O = p3.out[zb];
    if (zb < 2) {
#pragma unroll
      for (int ni = 0; ni < NI; ++ni) {
        const int col = ncol + ni * 16 + r16;
        const float bvv = bz[col] * bsc;
#pragma unroll
        for (int mi = 0; mi < MI; ++mi) {
          const int rowb = mrow + mi * 16 + quad * 4;
#pragma unroll
          for (int rr = 0; rr < 4; ++rr)
            O[(size_t)(rowb + rr) * 512 + col] = f2bf(acc[mi][ni][rr] + bvv);
        }
      }
    } else {
#pragma unroll
      for (int ni = 0; ni < NI; ++ni) {
        const int col = ncol + ni * 16 + r16;
        const float bvv = bz[col];
#pragma unroll
        for (int mi = 0; mi < MI; ++mi) {
          const int rowb = mrow + mi * 16 + quad * 4;
          const int bb = rowb >> 12;
          const int nn = rowb & 4095;
          ushort4 pk;
          pk.x = f2bf(acc[mi][ni][0] + bvv);
          pk.y = f2bf(acc[mi][ni][1] + bvv);
          pk.z = f2bf(acc[mi][ni][2] + bvv);
          pk.w = f2bf(acc[mi][ni][3] + bvv);
          *(ushort4*)&O[(((size_t)bb * 512 + col) << 12) + nn] = pk;
        }
      }
    }
  }
}

// ------- 8-wave, C-quadrant 4-phase pipelined NT GEMM (m201-style) -------
// BK=64, double-buffered LDS; per K-tile: 4 phases. Phases 1-3 issue their
// ds_reads BEFORE the phase barrier (latency hides under barrier + stage
// issue); compiler emits partial lgkmcnt(N) so MFMA starts as fragments
// arrive. Phase 0 is the rotation gate: ONE counted vmcnt per K-tile +
// barrier makes the whole staged tile visible; its reads must follow the
// gate. Quadrant walk (0,0)->(0,1)->(1,1)->(1,0) reuses held fragments.
// EPI 4: scores -> exp(acc) bf16 + atomic per-row sum into lbuf[z*4096+row].
// EPI 5: PV -> acc / lbuf[z*4096+row], bf16 out.
template <int BM, int BN, int WGM, int WGN, int EPI>
__global__ __launch_bounds__(512, 2) void gemm8p_k(
    const ushort_t* __restrict__ A, int lda,
    const ushort_t* __restrict__ Bm, int ldb,
    void* __restrict__ Cout, int ldc, int K,
    size_t azs, size_t bzs, size_t czs, float* __restrict__ lbuf) {
  constexpr int WTM = BM / WGM, WTN = BN / WGN;
  constexpr int MI = WTM / 16, NI = WTN / 16;
  constexpr int MH = MI / 2, NH = NI / 2;
  constexpr int ALD = BM / 64;        // A gload_lds per thread per K-tile
  constexpr int BLD = BN / 64;
  constexpr int TOT = ALD + BLD;
  constexpr int VMC = TOT / 4;        // loads staged in phase-0 group
  constexpr int AHALF = BM * 64;      // ushorts per A buffer
  constexpr int HALF = (BM + BN) * 64;

  extern __shared__ ushort_t lds8[];
  const int tid = threadIdx.x;
  const int lane = tid & 63;
  const int quad = lane >> 4;
  const int r16 = lane & 15;
  const int wid = tid >> 6;
  const int wm = wid / WGN, wn = wid % WGN;

  // XCD-clustered block swizzle (HW runs flat%8 on XCD flat%8)
  int bx, by, bz;
  {
    const int flat = blockIdx.x + (EPI == 4 ? 16 : 4) * (blockIdx.y + 16 * blockIdx.z);
    if constexpr (EPI == 4) {  // grid 16x16x4: 4x4 tile-chunks per XCD
      const int xcd = flat & 7, s = flat >> 3;
      const int w = s & 31, half = w >> 4, idx = w & 15;
      bx = (xcd & 3) * 4 + (idx & 3);
      by = ((xcd >> 2) + 2 * half) * 4 + (idx >> 2);
      bz = s >> 5;
    } else {                   // grid 4x16x4: x-siblings (shared Se panel) per XCD
      const int xcd = flat & 7, s = flat >> 3;
      bx = s & 3;
      const int yz = xcd + (s >> 2) * 8;
      by = yz & 15; bz = yz >> 4;
    }
  }
  const int m0 = by * BM, n0 = bx * BN, zb = bz;
  A += azs * zb;
  Bm += bzs * zb;
  const int NT = K >> 6;

  // per-thread stage sources (tile col offset added per stage) + LDS dests
  const ushort_t* src[TOT];
  ushort_t* dst[TOT];
#pragma unroll
  for (int l = 0; l < TOT; ++l) {
    const bool isA = l < ALD;
    const int li = isA ? l : l - ALD;
    const int s = li * 512 + tid;
    const int row = s >> 3;
    const int q = (s & 7) ^ (row & 7);  // proven CPR=8 chunk swizzle
    src[l] = (isA ? A + (size_t)(m0 + row) * lda
                  : Bm + (size_t)(n0 + row) * ldb) + (q << 3);
    dst[l] = lds8 + (isA ? 0 : AHALF) + (s << 3);
  }

  f32x4 acc[MI][NI] = {};

  // prologue: stage tile 0 into buffer 0
#pragma unroll
  for (int l = 0; l < TOT; ++l) async16(dst[l], src[l]);

  bf16x8 afq[MH][2], bfq[NH][2];

#pragma unroll 2
  for (int t = 0; t < NT; ++t) {
    const int nbuf = (t + 1) & 1;
    const ushort_t* Ab = lds8 + (t & 1) * HALF;
    const ushort_t* Bb = Ab + AHALF;
    // clamped source (dummy re-stage on last tile keeps the vmcnt ledger exact)
    const int koff = ((t + 1 < NT) ? t + 1 : NT - 1) << 6;

#define STAGEG(G)                                                              \
    { constexpr int S_ = ((G) * TOT) / 4, E_ = (((G) + 1) * TOT) / 4;          \
      _Pragma("unroll")                                                        \
      for (int l = S_; l < E_; ++l) async16(dst[l] + nbuf * HALF, src[l] + koff); }

#define LOADA(MHh)                                                             \
    _Pragma("unroll") for (int i = 0; i < MH; ++i)                             \
    _Pragma("unroll") for (int kf = 0; kf < 2; ++kf) {                         \
      const int lr = wm * WTM + ((MHh) * MH + i) * 16 + r16;                   \
      const int cc = (kf * 4 + quad) ^ (lr & 7);                               \
      afq[i][kf] = *reinterpret_cast<const bf16x8*>(&Ab[lr * 64 + cc * 8]); }

#define LOADB(NHh)                                                             \
    _Pragma("unroll") for (int j = 0; j < NH; ++j)                             \
    _Pragma("unroll") for (int kf = 0; kf < 2; ++kf) {                         \
      const int lr = wn * WTN + ((NHh) * NH + j) * 16 + r16;                   \
      const int cc = (kf * 4 + quad) ^ (lr & 7);                               \
      bfq[j][kf] = *reinterpret_cast<const bf16x8*>(&Bb[lr * 64 + cc * 8]); }

#define MMAQ(MHh, NHh)                                                         \
    __builtin_amdgcn_s_setprio(1);                                             \
    _Pragma("unroll") for (int i = 0; i < MH; ++i)                             \
    _Pragma("unroll") for (int j = 0; j < NH; ++j)                             \
    _Pragma("unroll") for (int kf = 0; kf < 2; ++kf)                           \
      acc[(MHh) * MH + i][(NHh) * NH + j] =                                    \
          __builtin_amdgcn_mfma_f32_16x16x32_bf16(                             \
              afq[i][kf], bfq[j][kf], acc[(MHh) * MH + i][(NHh) * NH + j],     \
              0, 0, 0);                                                        \
    __builtin_amdgcn_s_setprio(0);

    // phase 0 : rotation gate + quadrant (0,0).
    // Reads MUST follow the vmcnt+barrier; load/MFMA region left unwalled so
    // the compiler interleaves partial lgkmcnt waits with the MFMAs.
    STAGEG(0)
    asm volatile("s_waitcnt vmcnt(%0)" :: "i"(VMC) : "memory");
    __builtin_amdgcn_s_barrier();
    __builtin_amdgcn_sched_barrier(0);  // pin rotated-buffer reads below gate
    LOADA(0)
    LOADB(0)
    MMAQ(0, 0)
    __builtin_amdgcn_sched_barrier(0);
    __builtin_amdgcn_s_barrier();
    // phase 1 : (0,1) — reads first (buffer stable), keep A frags
    LOADB(1)
    STAGEG(1)
    __builtin_amdgcn_sched_barrier(0);  // pin reads+stage above barrier
    __builtin_amdgcn_s_barrier();
    MMAQ(0, 1)
    __builtin_amdgcn_sched_barrier(0);
    __builtin_amdgcn_s_barrier();
    // phase 2 : (1,1) — reads first, keep B frags
    LOADA(1)
    STAGEG(2)
    __builtin_amdgcn_sched_barrier(0);
    __builtin_amdgcn_s_barrier();
    MMAQ(1, 1)
    __builtin_amdgcn_sched_barrier(0);
    __builtin_amdgcn_s_barrier();
    // phase 3 : (1,0) — reads first, keep A frags
    LOADB(0)
    STAGEG(3)
    __builtin_amdgcn_sched_barrier(0);
    __builtin_amdgcn_s_barrier();
    MMAQ(1, 0)
    __builtin_amdgcn_sched_barrier(0);
    __builtin_amdgcn_s_barrier();
#undef STAGEG
#undef LOADA
#undef LOADB
#undef MMAQ
  }

  const int mrow = m0 + wm * WTM;
  const int ncol = n0 + wn * WTN;
  if constexpr (EPI == 4) {  // scores: exp + bf16 + atomic row sum
    ushort_t* C = (ushort_t*)Cout + czs * zb;
    float* Lz = lbuf + (size_t)zb * 4096;
#pragma unroll
    for (int mi = 0; mi < MI; ++mi) {
#pragma unroll
      for (int rr = 0; rr < 4; ++rr) {
        const int row = mrow + mi * 16 + quad * 4 + rr;
        float ps = 0.f;
#pragma unroll
        for (int ni = 0; ni < NI; ++ni) {
          const int col = ncol + ni * 16 + r16;
          const ushort_t ub = f2bf(__expf(acc[mi][ni][rr]));
          C[(size_t)row * ldc + col] = ub;
          ps += bf2f(ub);  // sum the ROUNDED values so l matches PV's MFMA sum
        }
#pragma unroll
        for (int o = 1; o < 16; o <<= 1) ps += __shfl_xor(ps, o, 64);
        if (r16 == 0) atomicAdd(&Lz[row], ps);
      }
    }
  } else {  // EPI == 5: PV, divide by row sum, bf16 out
    ushort_t* C = (ushort_t*)Cout + czs * zb;
    const float* Lz = lbuf + (size_t)zb * 4096;
#pragma unroll
    for (int mi = 0; mi < MI; ++mi) {
#pragma unroll
      for (int rr = 0; rr < 4; ++rr) {
        const int row = mrow + mi * 16 + quad * 4 + rr;
        const float inv = 1.f / Lz[row];
#pragma unroll
        for (int ni = 0; ni < NI; ++ni) {
          const int col = ncol + ni * 16 + r16;
          C[(size_t)row * ldc + col] = f2bf(acc[mi][ni][rr] * inv);
        }
      }
    }
  }
}

extern "C" void kernel_launch(void* const* d_in, const int* in_sizes, int n_in,
                              void* d_out, int out_size, void* d_ws, size_t ws_size,
                              hipStream_t stream) {
  const float* x  = (const float*)d_in[0];
  const float* gs = (const float*)d_in[1];
  const float* gb = (const float*)d_in[2];
  const float* wq = (const float*)d_in[3];
  const float* bq = (const float*)d_in[4];
  const float* wk = (const float*)d_in[5];
  const float* bk = (const float*)d_in[6];
  const float* wv = (const float*)d_in[7];
  const float* bv = (const float*)d_in[8];
  const float* wo = (const float*)d_in[9];
  const float* bo = (const float*)d_in[10];
  float* out = (float*)d_out;

  const size_t HNC = (size_t)4 * 4096 * 512;
  char* w = (char*)d_ws;
  float* stats  = (float*)w;    w += 4096;
  float* Ls     = (float*)w;    w += (size_t)4 * 4096 * 4;  // exp row sums
  ushort_t* wb  = (ushort_t*)w; w += (size_t)4 * 262144 * 2;
  ushort_t* h   = (ushort_t*)w; w += HNC * 2;  // GN out; reused as O
  ushort_t* q   = (ushort_t*)w; w += HNC * 2;
  ushort_t* kk  = (ushort_t*)w; w += HNC * 2;
  ushort_t* vt  = (ushort_t*)w; w += HNC * 2;  // V transposed [B,C,N]
  ushort_t* Se  = (ushort_t*)w; w += (size_t)4 * 4096 * 4096 * 2;  // exp(S) bf16

  const float sc = 0.044194173824159216f;  // 512^-0.5, folded into wq/bq

  static bool attr_done = false;
  if (!attr_done) {
    (void)hipFuncSetAttribute((const void*)gemm8p_k<256, 256, 2, 4, 4>,
                              hipFuncAttributeMaxDynamicSharedMemorySize, 131072);
    (void)hipFuncSetAttribute((const void*)gemm8p_k<256, 128, 4, 2, 5>,
                              hipFuncAttributeMaxDynamicSharedMemorySize, 98304);
    attr_done = true;
  }

  gn_stats_k<<<128, 256, 0, stream>>>(x, stats);
  gn_apply_k<<<8192, 256, 0, stream>>>(x, stats, gs, gb, h);
  Ptr4 wsrc;
  wsrc.src[0] = wq; wsrc.src[1] = wk; wsrc.src[2] = wv; wsrc.src[3] = wo;
  wsrc.wsc[0] = sc; wsrc.wsc[1] = 1.f; wsrc.wsc[2] = 1.f; wsrc.wsc[3] = 1.f;
  cvt_all_k<<<4096, 256, 0, stream>>>(wsrc, wb);
  hipMemsetAsync(Ls, 0, (size_t)4 * 4096 * 4, stream);

  Ptr3 qkv;
  qkv.bias[0] = bq; qkv.bias[1] = bk; qkv.bias[2] = bv;
  qkv.out[0] = q; qkv.out[1] = kk; qkv.out[2] = vt;
  qkv.bs[0] = sc; qkv.bs[1] = 1.f; qkv.bs[2] = 1.f;
  gemm_nt_k<128, 128, 32, 3><<<dim3(4, 128, 3), 256, 0, stream>>>(
      h, 512, wb, 512, nullptr, 0, nullptr, nullptr, 1.f, 512,
      0, 262144, 0, qkv, nullptr);

  // Se[z] = exp(q k^T) bf16 + atomic row sums (256x256, quadrant pipeline)
  gemm8p_k<256, 256, 2, 4, 4><<<dim3(16, 16, 4), 512, 131072, stream>>>(
      q, 512, kk, 512, Se, 4096, 512,
      (size_t)4096 * 512, (size_t)4096 * 512, (size_t)4096 * 4096, Ls);
  // O[z] = (Se V) / l, bf16 into h (256x128, quadrant pipeline)
  gemm8p_k<256, 128, 4, 2, 5><<<dim3(4, 16, 4), 512, 98304, stream>>>(
      Se, 4096, vt, 4096, h, 512, 4096,
      (size_t)4096 * 4096, (size_t)512 * 4096, (size_t)4096 * 512, Ls);

  // out = x + O @ wo^T + bo, transposed back to [B,C,H,W]
  Ptr3 e0{};
  gemm_nt_k<128, 128, 32, 2><<<dim3(4, 128, 1), 256, 0, stream>>>(
      h, 512, wb + (size_t)3 * 262144, 512, out, 512, bo, x, 1.f, 512,
      0, 0, 0, e0, nullptr);
}

// Round 4
// 353.350 us; speedup vs baseline: 1.3122x; 1.1161x over previous
//
#include <hip/hip_runtime.h>
#include <cstdint>
#include <cstddef>

typedef unsigned short ushort_t;
typedef __attribute__((ext_vector_type(8))) __bf16 bf16x8;
typedef __attribute__((ext_vector_type(4))) float f32x4;

#define DEVINL __device__ __forceinline__

DEVINL ushort_t f2bf(float f) {
  union { __bf16 b; ushort_t u; } v;
  v.b = (__bf16)f;
  return v.u;
}
DEVINL float bf2f(ushort_t u) {
  union { unsigned u; float f; } v; v.u = ((unsigned)u) << 16;
  return v.f;
}

DEVINL float wred_sum(float x) {
#pragma unroll
  for (int o = 32; o > 0; o >>= 1) x += __shfl_xor(x, o, 64);
  return x;
}

// async global->LDS, 16B per lane (global_load_lds_dwordx4)
DEVINL void async16(ushort_t* lds, const ushort_t* g) {
  __builtin_amdgcn_global_load_lds(
      (__attribute__((address_space(1))) const unsigned int*)g,
      (__attribute__((address_space(3))) unsigned int*)lds, 16, 0, 0);
}

template <int CPR>
DEVINL int fswz(int r) {
  if constexpr (CPR == 4) return (r >> 2) & 3;
  else return r & 7;  // CPR==8
}

// ---------------- GroupNorm ----------------
__global__ __launch_bounds__(256) void gn_stats_k(const float* __restrict__ x,
                                                  float* __restrict__ stats) {
  const int bg = blockIdx.x;
  const float4* base = (const float4*)(x + ((size_t)bg << 16));
  float s = 0.f, q = 0.f;
  for (int i = threadIdx.x; i < 16384; i += 256) {
    float4 f = base[i];
    s += f.x + f.y + f.z + f.w;
    q += f.x * f.x + f.y * f.y + f.z * f.z + f.w * f.w;
  }
  s = wred_sum(s);
  q = wred_sum(q);
  __shared__ float rs[4], rq[4];
  const int lane = threadIdx.x & 63, wid = threadIdx.x >> 6;
  if (lane == 0) { rs[wid] = s; rq[wid] = q; }
  __syncthreads();
  if (threadIdx.x == 0) {
    float S = rs[0] + rs[1] + rs[2] + rs[3];
    float Q = rq[0] + rq[1] + rq[2] + rq[3];
    float mean = S * (1.f / 65536.f);
    float var = Q * (1.f / 65536.f) - mean * mean;
    stats[2 * bg] = mean;
    stats[2 * bg + 1] = rsqrtf(var + 1e-5f);
  }
}

__global__ __launch_bounds__(256) void gn_apply_k(const float* __restrict__ x,
                                                  const float* __restrict__ stats,
                                                  const float* __restrict__ gs,
                                                  const float* __restrict__ gb,
                                                  ushort_t* __restrict__ h) {
  __shared__ ushort_t tile[32][33];
  const int bid = blockIdx.x;
  const int b = bid >> 11;
  const int r = bid & 2047;
  const int ct = r >> 7, nt = r & 127;
  const int c0 = ct << 5, n0 = nt << 5;
  const int tx = threadIdx.x & 31, ty = threadIdx.x >> 5;
#pragma unroll
  for (int i = 0; i < 4; ++i) {
    const int c = c0 + ty + i * 8;
    const float mean = stats[2 * (b * 32 + (c >> 4))];
    const float rstd = stats[2 * (b * 32 + (c >> 4)) + 1];
    const float xv = x[(((size_t)b * 512 + c) << 12) + n0 + tx];
    tile[ty + i * 8][tx] = f2bf((xv - mean) * rstd * gs[c] + gb[c]);
  }
  __syncthreads();
#pragma unroll
  for (int i = 0; i < 4; ++i) {
    const int n = n0 + ty + i * 8;
    h[(((size_t)b << 12) + n) * 512 + c0 + tx] = tile[tx][ty + i * 8];
  }
}

// fp32 -> bf16 convert with per-matrix scale (sc folded into wq)
struct Ptr4 { const float* src[4]; float wsc[4]; };
__global__ __launch_bounds__(256) void cvt_all_k(Ptr4 s, ushort_t* __restrict__ dst) {
  const int i = blockIdx.x * 256 + threadIdx.x;
  const int m = i >> 18;
  dst[i] = f2bf(s.src[m][i & 262143] * s.wsc[m]);
}

// ---------------- NT GEMM (128x128, 2-barrier): C[M,N] = A[M,K] * B[N,K]^T ----
// EPI 2: fp32 transposed out + resid + bias (final projection).
// EPI 3: QKV fused, z picks weight/bias/out; z==2 (V) writes transposed [C][N].
struct Ptr3 { const float* bias[3]; ushort_t* out[3]; float bs[3]; };

template <int BM, int BN, int BK, int EPI>
__global__ __launch_bounds__(256) void gemm_nt_k(
    const ushort_t* __restrict__ A, int lda, const ushort_t* __restrict__ Bm, int ldb,
    void* __restrict__ Cout, int ldc, const float* __restrict__ bias,
    const float* __restrict__ resid, float scale, int K,
    size_t azs, size_t bzs, size_t czs, Ptr3 p3) {
  constexpr int CPR = BK / 8;
  constexpr int WTM = BM / 2, WTN = BN / 2;
  constexpr int MI = WTM / 16, NI = WTN / 16;
  constexpr int AR = (BM * CPR) / 256;
  constexpr int BR = (BN * CPR) / 256;
  __shared__ ushort_t Als[BM * BK];
  __shared__ ushort_t Bls[BN * BK];
  const int tid = threadIdx.x;
  const int lane = tid & 63;
  const int wid = tid >> 6;
  const int quad = lane >> 4;
  const int r16 = lane & 15;
  const int wm = wid >> 1, wn = wid & 1;
  const int m0 = blockIdx.y * BM;
  const int n0 = blockIdx.x * BN;
  const int zb = blockIdx.z;

  A += azs * zb;
  Bm += bzs * zb;

  f32x4 acc[MI][NI] = {};

  for (int kt = 0; kt < K; kt += BK) {
#pragma unroll
    for (int r = 0; r < AR; ++r) {
      const int s = r * 256 + tid;
      const int row = s / CPR;
      const int q = (s % CPR) ^ fswz<CPR>(row);
      async16(&Als[s << 3], A + (size_t)(m0 + row) * lda + kt + (q << 3));
    }
#pragma unroll
    for (int r = 0; r < BR; ++r) {
      const int s = r * 256 + tid;
      const int row = s / CPR;
      const int q = (s % CPR) ^ fswz<CPR>(row);
      async16(&Bls[s << 3], Bm + (size_t)(n0 + row) * ldb + kt + (q << 3));
    }
    __syncthreads();
#pragma unroll
    for (int kf = 0; kf < BK / 32; ++kf) {
      bf16x8 af[MI], bfr[NI];
#pragma unroll
      for (int mi = 0; mi < MI; ++mi) {
        const int lr = wm * WTM + mi * 16 + r16;
        const int ch = kf * 4 + quad;
        af[mi] = *reinterpret_cast<const bf16x8*>(
            &Als[(lr * CPR + (ch ^ fswz<CPR>(lr))) << 3]);
      }
#pragma unroll
      for (int ni = 0; ni < NI; ++ni) {
        const int lr = wn * WTN + ni * 16 + r16;
        const int ch = kf * 4 + quad;
        bfr[ni] = *reinterpret_cast<const bf16x8*>(
            &Bls[(lr * CPR + (ch ^ fswz<CPR>(lr))) << 3]);
      }
#pragma unroll
      for (int mi = 0; mi < MI; ++mi)
#pragma unroll
        for (int ni = 0; ni < NI; ++ni)
          acc[mi][ni] = __builtin_amdgcn_mfma_f32_16x16x32_bf16(
              af[mi], bfr[ni], acc[mi][ni], 0, 0, 0);
    }
    __syncthreads();
  }

  const int mrow = m0 + wm * WTM;
  const int ncol = n0 + wn * WTN;
  if constexpr (EPI == 2) {  // final: fp32 transposed out + resid + bias
    float* C = (float*)Cout;
#pragma unroll
    for (int ni = 0; ni < NI; ++ni) {
      const int col = ncol + ni * 16 + r16;
      const float bvv = bias[col];
#pragma unroll
      for (int mi = 0; mi < MI; ++mi) {
        const int rowb = mrow + mi * 16 + quad * 4;
        const int bb = rowb >> 12;
        const int nl = rowb & 4095;
        const size_t base = (((size_t)bb * 512 + col) << 12) + nl;
        const float4 rv = *(const float4*)&resid[base];
        float4 ov;
        ov.x = rv.x + acc[mi][ni][0] + bvv;
        ov.y = rv.y + acc[mi][ni][1] + bvv;
        ov.z = rv.z + acc[mi][ni][2] + bvv;
        ov.w = rv.w + acc[mi][ni][3] + bvv;
        *(float4*)&C[base] = ov;
      }
    }
  } else if constexpr (EPI == 3) {  // QKV, z picks weight/bias/out; z==2 V^T
    const float* bz = p3.bias[zb];
    const float bsc = p3.bs[zb];
    ushort_t* O = p3.out[zb];
    if (zb < 2) {
#pragma unroll
      for (int ni = 0; ni < NI; ++ni) {
        const int col = ncol + ni * 16 + r16;
        const float bvv = bz[col] * bsc;
#pragma unroll
        for (int mi = 0; mi < MI; ++mi) {
          const int rowb = mrow + mi * 16 + quad * 4;
#pragma unroll
          for (int rr = 0; rr < 4; ++rr)
            O[(size_t)(rowb + rr) * 512 + col] = f2bf(acc[mi][ni][rr] + bvv);
        }
      }
    } else {
#pragma unroll
      for (int ni = 0; ni < NI; ++ni) {
        const int col = ncol + ni * 16 + r16;
        const float bvv = bz[col];
#pragma unroll
        for (int mi = 0; mi < MI; ++mi) {
          const int rowb = mrow + mi * 16 + quad * 4;
          const int bb = rowb >> 12;
          const int nn = rowb & 4095;
          ushort4 pk;
          pk.x = f2bf(acc[mi][ni][0] + bvv);
          pk.y = f2bf(acc[mi][ni][1] + bvv);
          pk.z = f2bf(acc[mi][ni][2] + bvv);
          pk.w = f2bf(acc[mi][ni][3] + bvv);
          *(ushort4*)&O[(((size_t)bb * 512 + col) << 12) + nn] = pk;
        }
      }
    }
  }
}

// ------- 8-wave, ONE-barrier-per-K-tile pipelined NT GEMM -------
// BK=64, double-buffered LDS. Per tile: drain lgkm+vm, single barrier,
// stage the whole next tile (into the other buffer), then an UNWALLED
// region of 24 ds_read_b128 + 64 MFMA that the compiler pipelines with
// partial lgkmcnt waits. No intra-tile barriers: reads hit the stable
// buffer, DMAs hit the other one. Stage-after-barrier prevents DMA
// landing in a buffer a slow wave still reads.
// EPI 4: scores -> exp(acc) bf16 store (no reduce, no atomics).
// EPI 5: PV -> acc / l, l computed IN-KERNEL via MFMA with all-ones B
//        (acc_l[i][rr] = row sum, exactly at the epilogue's row).
template <int BM, int BN, int WGM, int WGN, int EPI>
__global__ __launch_bounds__(512, 2) void gemm8l_k(
    const ushort_t* __restrict__ A, int lda,
    const ushort_t* __restrict__ Bm, int ldb,
    void* __restrict__ Cout, int ldc, int K,
    size_t azs, size_t bzs, size_t czs) {
  constexpr int WTM = BM / WGM, WTN = BN / WGN;
  constexpr int MI = WTM / 16, NI = WTN / 16;
  constexpr int MH = MI / 2;
  constexpr int ALD = BM / 64;        // A gload_lds per thread per K-tile
  constexpr int BLD = BN / 64;
  constexpr int TOT = ALD + BLD;
  constexpr int AHALF = BM * 64;      // ushorts per A buffer
  constexpr int HALF = (BM + BN) * 64;

  extern __shared__ ushort_t lds8[];
  const int tid = threadIdx.x;
  const int lane = tid & 63;
  const int quad = lane >> 4;
  const int r16 = lane & 15;
  const int wid = tid >> 6;
  const int wm = wid / WGN, wn = wid % WGN;

  // XCD-clustered block swizzle (HW runs flat%8 on XCD flat%8)
  int bx, by, bz;
  {
    const int flat = blockIdx.x + (EPI == 4 ? 16 : 4) * (blockIdx.y + 16 * blockIdx.z);
    if constexpr (EPI == 4) {  // grid 16x16x4: 4x4 tile-chunks per XCD
      const int xcd = flat & 7, s = flat >> 3;
      const int w = s & 31, half = w >> 4, idx = w & 15;
      bx = (xcd & 3) * 4 + (idx & 3);
      by = ((xcd >> 2) + 2 * half) * 4 + (idx >> 2);
      bz = s >> 5;
    } else {                   // grid 4x16x4: x-siblings (shared Se panel) per XCD
      const int xcd = flat & 7, s = flat >> 3;
      bx = s & 3;
      const int yz = xcd + (s >> 2) * 8;
      by = yz & 15; bz = yz >> 4;
    }
  }
  const int m0 = by * BM, n0 = bx * BN, zb = bz;
  A += azs * zb;
  Bm += bzs * zb;
  const int NT = K >> 6;

  // per-thread stage sources + LDS dest offsets (proven CPR=8 chunk swizzle)
  const ushort_t* src[TOT];
  int dsto[TOT];
#pragma unroll
  for (int l = 0; l < TOT; ++l) {
    const bool isA = l < ALD;
    const int li = isA ? l : l - ALD;
    const int s = li * 512 + tid;
    const int row = s >> 3;
    const int q = (s & 7) ^ (row & 7);
    src[l] = (isA ? A + (size_t)(m0 + row) * lda
                  : Bm + (size_t)(n0 + row) * ldb) + (q << 3);
    dsto[l] = (isA ? 0 : AHALF) + (s << 3);
  }

  f32x4 acc[MI][NI] = {};
  f32x4 acc_l[MI] = {};
  bf16x8 ones;
  {
    union { ushort_t u; __bf16 b; } o1; o1.u = 0x3F80;  // bf16 1.0
#pragma unroll
    for (int j = 0; j < 8; ++j) ones[j] = o1.b;
  }

  // prologue: stage tile 0 into buffer 0
#pragma unroll
  for (int l = 0; l < TOT; ++l) async16(lds8 + dsto[l], src[l]);

  for (int t = 0; t < NT; ++t) {
    const int nbuf = (t + 1) & 1;
    const ushort_t* Ab = lds8 + (t & 1) * HALF;
    const ushort_t* Bb = Ab + AHALF;
    // clamped source (dummy re-stage on last tile keeps the ledger uniform)
    const int koff = ((t + 1 < NT) ? t + 1 : NT - 1) << 6;

    // gate: my reads are physically done (lgkm) and my tile-t DMAs landed
    // (vm; issued a full tile ago, so cheap). Barrier makes it global.
    asm volatile("s_waitcnt vmcnt(0) lgkmcnt(0)" ::: "memory");
    __builtin_amdgcn_s_barrier();

    // stage the whole next tile (other buffer) — after the barrier, so no
    // DMA can land in a buffer a slower wave still reads.
#pragma unroll
    for (int l = 0; l < TOT; ++l)
      async16(lds8 + nbuf * HALF + dsto[l], src[l] + koff);

    // unwalled read+MFMA region: full B, A in halves
    bf16x8 bfr[NI][2], af[MH][2];
#pragma unroll
    for (int ni = 0; ni < NI; ++ni)
#pragma unroll
      for (int kf = 0; kf < 2; ++kf) {
        const int lr = wn * WTN + ni * 16 + r16;
        const int cc = (kf * 4 + quad) ^ (lr & 7);
        bfr[ni][kf] = *reinterpret_cast<const bf16x8*>(&Bb[lr * 64 + cc * 8]);
      }
#pragma unroll
    for (int h = 0; h < 2; ++h) {
#pragma unroll
      for (int i = 0; i < MH; ++i)
#pragma unroll
        for (int kf = 0; kf < 2; ++kf) {
          const int lr = wm * WTM + (h * MH + i) * 16 + r16;
          const int cc = (kf * 4 + quad) ^ (lr & 7);
          af[i][kf] = *reinterpret_cast<const bf16x8*>(&Ab[lr * 64 + cc * 8]);
        }
      __builtin_amdgcn_s_setprio(1);
#pragma unroll
      for (int i = 0; i < MH; ++i)
#pragma unroll
        for (int ni = 0; ni < NI; ++ni)
#pragma unroll
          for (int kf = 0; kf < 2; ++kf)
            acc[h * MH + i][ni] = __builtin_amdgcn_mfma_f32_16x16x32_bf16(
                af[i][kf], bfr[ni][kf], acc[h * MH + i][ni], 0, 0, 0);
      if constexpr (EPI == 5) {
#pragma unroll
        for (int i = 0; i < MH; ++i)
#pragma unroll
          for (int kf = 0; kf < 2; ++kf)
            acc_l[h * MH + i] = __builtin_amdgcn_mfma_f32_16x16x32_bf16(
                af[i][kf], ones, acc_l[h * MH + i], 0, 0, 0);
      }
      __builtin_amdgcn_s_setprio(0);
    }
  }
  // drain trailing dummy-stage DMAs so they can't land in a successor
  // block's LDS after this block retires.
  asm volatile("s_waitcnt vmcnt(0)" ::: "memory");

  const int mrow = m0 + wm * WTM;
  const int ncol = n0 + wn * WTN;
  if constexpr (EPI == 4) {  // scores: exp + bf16 store, no reduce
    ushort_t* C = (ushort_t*)Cout + czs * zb;
#pragma unroll
    for (int mi = 0; mi < MI; ++mi) {
#pragma unroll
      for (int rr = 0; rr < 4; ++rr) {
        const int row = mrow + mi * 16 + quad * 4 + rr;
#pragma unroll
        for (int ni = 0; ni < NI; ++ni) {
          const int col = ncol + ni * 16 + r16;
          C[(size_t)row * ldc + col] = f2bf(__expf(acc[mi][ni][rr]));
        }
      }
    }
  } else {  // EPI == 5: PV, divide by in-register row sum, bf16 out
    ushort_t* C = (ushort_t*)Cout + czs * zb;
#pragma unroll
    for (int mi = 0; mi < MI; ++mi) {
#pragma unroll
      for (int rr = 0; rr < 4; ++rr) {
        const int row = mrow + mi * 16 + quad * 4 + rr;
        const float inv = 1.f / acc_l[mi][rr];
#pragma unroll
        for (int ni = 0; ni < NI; ++ni) {
          const int col = ncol + ni * 16 + r16;
          C[(size_t)row * ldc + col] = f2bf(acc[mi][ni][rr] * inv);
        }
      }
    }
  }
}

extern "C" void kernel_launch(void* const* d_in, const int* in_sizes, int n_in,
                              void* d_out, int out_size, void* d_ws, size_t ws_size,
                              hipStream_t stream) {
  const float* x  = (const float*)d_in[0];
  const float* gs = (const float*)d_in[1];
  const float* gb = (const float*)d_in[2];
  const float* wq = (const float*)d_in[3];
  const float* bq = (const float*)d_in[4];
  const float* wk = (const float*)d_in[5];
  const float* bk = (const float*)d_in[6];
  const float* wv = (const float*)d_in[7];
  const float* bv = (const float*)d_in[8];
  const float* wo = (const float*)d_in[9];
  const float* bo = (const float*)d_in[10];
  float* out = (float*)d_out;

  const size_t HNC = (size_t)4 * 4096 * 512;
  char* w = (char*)d_ws;
  float* stats  = (float*)w;    w += 4096;
  ushort_t* wb  = (ushort_t*)w; w += (size_t)4 * 262144 * 2;
  ushort_t* h   = (ushort_t*)w; w += HNC * 2;  // GN out; reused as O
  ushort_t* q   = (ushort_t*)w; w += HNC * 2;
  ushort_t* kk  = (ushort_t*)w; w += HNC * 2;
  ushort_t* vt  = (ushort_t*)w; w += HNC * 2;  // V transposed [B,C,N]
  ushort_t* Se  = (ushort_t*)w; w += (size_t)4 * 4096 * 4096 * 2;  // exp(S) bf16

  const float sc = 0.044194173824159216f;  // 512^-0.5, folded into wq/bq

  static bool attr_done = false;
  if (!attr_done) {
    (void)hipFuncSetAttribute((const void*)gemm8l_k<256, 256, 2, 4, 4>,
                              hipFuncAttributeMaxDynamicSharedMemorySize, 131072);
    (void)hipFuncSetAttribute((const void*)gemm8l_k<256, 128, 4, 2, 5>,
                              hipFuncAttributeMaxDynamicSharedMemorySize, 98304);
    attr_done = true;
  }

  gn_stats_k<<<128, 256, 0, stream>>>(x, stats);
  gn_apply_k<<<8192, 256, 0, stream>>>(x, stats, gs, gb, h);
  Ptr4 wsrc;
  wsrc.src[0] = wq; wsrc.src[1] = wk; wsrc.src[2] = wv; wsrc.src[3] = wo;
  wsrc.wsc[0] = sc; wsrc.wsc[1] = 1.f; wsrc.wsc[2] = 1.f; wsrc.wsc[3] = 1.f;
  cvt_all_k<<<4096, 256, 0, stream>>>(wsrc, wb);

  Ptr3 qkv;
  qkv.bias[0] = bq; qkv.bias[1] = bk; qkv.bias[2] = bv;
  qkv.out[0] = q; qkv.out[1] = kk; qkv.out[2] = vt;
  qkv.bs[0] = sc; qkv.bs[1] = 1.f; qkv.bs[2] = 1.f;
  gemm_nt_k<128, 128, 32, 3><<<dim3(4, 128, 3), 256, 0, stream>>>(
      h, 512, wb, 512, nullptr, 0, nullptr, nullptr, 1.f, 512,
      0, 262144, 0, qkv);

  // Se[z] = exp(q k^T) bf16 (one-barrier pipeline, no reduce/atomics)
  gemm8l_k<256, 256, 2, 4, 4><<<dim3(16, 16, 4), 512, 131072, stream>>>(
      q, 512, kk, 512, Se, 4096, 512,
      (size_t)4096 * 512, (size_t)4096 * 512, (size_t)4096 * 4096);
  // O[z] = (Se V) / l, l computed in-kernel via ones-MFMA
  gemm8l_k<256, 128, 4, 2, 5><<<dim3(4, 16, 4), 512, 98304, stream>>>(
      Se, 4096, vt, 4096, h, 512, 4096,
      (size_t)4096 * 4096, (size_t)512 * 4096, (size_t)4096 * 512);

  // out = x + O @ wo^T + bo, transposed back to [B,C,H,W]
  Ptr3 e0{};
  gemm_nt_k<128, 128, 32, 2><<<dim3(4, 128, 1), 256, 0, stream>>>(
      h, 512, wb + (size_t)3 * 262144, 512, out, 512, bo, x, 1.f, 512,
      0, 0, 0, e0);
}